// Round 4
// baseline (302.193 us; speedup 1.0000x reference)
//
#include <hip/hip_runtime.h>

typedef unsigned int uint;
typedef unsigned short ushort;
typedef __attribute__((ext_vector_type(8))) short  short8;   // 8 bf16 (4 VGPRs)
typedef __attribute__((ext_vector_type(8))) unsigned short u16x8;
typedef __attribute__((ext_vector_type(16))) float f32x16;   // 32x32 MFMA accumulator

// round-to-nearest-even f32 -> bf16
__device__ __forceinline__ ushort f2b(float f) {
    uint u = __float_as_uint(f);
    u += 0x7FFFu + ((u >> 16) & 1u);
    return (ushort)(u >> 16);
}

__device__ __forceinline__ void async16(const void* g, void* l) {
    __builtin_amdgcn_global_load_lds(
        (const __attribute__((address_space(1))) void*)g,
        (__attribute__((address_space(3))) void*)l,
        16, 0, 0);
}

// ---------------------------------------------------------------------------
// Kernel 1: expand c (16,16,256) f32 -> Wt bf16 [N=4096][K=4096]
//   Wt[j*256+k][i*256+m] = c[j,i,(k-m)&255]
// ---------------------------------------------------------------------------
__global__ __launch_bounds__(256) void expand_w(const float* __restrict__ c,
                                                ushort* __restrict__ Wt) {
    const int j = blockIdx.x >> 4;
    const int i = blockIdx.x & 15;
    __shared__ ushort crev2[512];
    const float* cs = c + (size_t)(j * 16 + i) * 256;
    const int t = threadIdx.x;
    {
        ushort b = f2b(cs[(256 - t) & 255]);
        crev2[t] = b;
        crev2[t + 256] = b;
    }
    __syncthreads();
    const int tr = t >> 5;
    const int tm = (t & 31) * 8;
    for (int rb = 0; rb < 256; rb += 8) {
        const int k = rb + tr;
        u16x8 v;
#pragma unroll
        for (int u = 0; u < 8; ++u) v[u] = crev2[tm + u - k + 256];
        *(u16x8*)&Wt[(size_t)(j * 256 + k) * 4096 + i * 256 + tm] = v;
    }
}

// ---------------------------------------------------------------------------
// Kernel 2: x f32 -> bf16
// ---------------------------------------------------------------------------
__global__ __launch_bounds__(256) void conv_x(const float4* __restrict__ x,
                                              u16x8* __restrict__ xb, int n8) {
    int idx = blockIdx.x * blockDim.x + threadIdx.x;
    const int stride = gridDim.x * blockDim.x;
    for (; idx < n8; idx += stride) {
        float4 a = x[idx * 2];
        float4 b = x[idx * 2 + 1];
        u16x8 o;
        o[0] = f2b(a.x); o[1] = f2b(a.y); o[2] = f2b(a.z); o[3] = f2b(a.w);
        o[4] = f2b(b.x); o[5] = f2b(b.y); o[6] = f2b(b.z); o[7] = f2b(b.w);
        xb[idx] = o;
    }
}

// ---------------------------------------------------------------------------
// Kernel 3: 256x256-tile 8-phase GEMM, 32x32x16 MFMA (T1+T2+T3+T4+T5)
//   C[8192][4096] = A[8192][4096] * Bt[4096][4096]^T + bias
// 512 thr = 8 waves (2M x 4N), per-wave 128x64 out = 4 mtiles x 2 ntiles of
// 32x32. BK=64 (4 k-slices of 16), 2 K-tiles/iter. LDS 128 KiB: 2 bufs x
// 4 slots(A0,A1,B0,B1) x [128][64] bf16.
// T2 swizzle (3-bit): 16B-slot s' = s ^ (row&7); inverse on GLOBAL source
// (linear gload_lds dest) + same XOR on ds_read col. Bank-verified 0-conflict.
// ---------------------------------------------------------------------------
#define BAR()   __builtin_amdgcn_s_barrier()
#define LGKM0() asm volatile("s_waitcnt lgkmcnt(0)" ::: "memory")
#define VMC6()  asm volatile("s_waitcnt vmcnt(6)" ::: "memory")
#define VMC0()  asm volatile("s_waitcnt vmcnt(0)" ::: "memory")
#define PRIO1() __builtin_amdgcn_s_setprio(1)
#define PRIO0() __builtin_amdgcn_s_setprio(0)

__global__ __launch_bounds__(512, 2) void gemm256(const ushort* __restrict__ A,
                                                  const ushort* __restrict__ Bt,
                                                  const float* __restrict__ bias,
                                                  float* __restrict__ C) {
    constexpr int K = 4096, N = 4096;
    __shared__ __align__(16) ushort lds[65536];  // 128 KiB

    const int tid  = threadIdx.x;
    const int wave = tid >> 6;
    const int lane = tid & 63;
    const int wr   = wave >> 2;       // 0..1  (M half)
    const int wc   = wave & 3;        // 0..3  (N quarter)
    const int lrow = lane & 31;       // 32x32 fragment row/col
    const int khi  = lane >> 5;       // k-offset group: k = khi*8 + j

    // T1: XCD 8x8-square swizzle (each XCD gets a contiguous 8bm x 8bn square)
    const int wg  = (int)blockIdx.x;
    const int xcd = wg & 7;
    const int idx = wg >> 3;
    const int bm  = (xcd & 3) * 8 + (idx & 7);   // 32 M-tiles
    const int bn  = (xcd >> 2) * 8 + (idx >> 3); // 16 N-tiles

    // staging: thread t covers linear LDS bytes [t*16,t*16+16) (+8KiB) of a
    // 16 KiB half-tile; source col carries the inverse swizzle
    const int r0  = tid >> 3;                              // 0..63
    const int cst = ((tid & 7) << 3) ^ ((r0 & 7) << 3);    // elem col, pre-swz
    const ushort* gA  = A  + (size_t)(bm * 256 + r0) * K + cst;
    const ushort* gB  = Bt + (size_t)(bn * 256 + r0) * K + cst;
    const ushort* gA2 = gA + (size_t)128 * K;
    const ushort* gB2 = gB + (size_t)128 * K;
    const size_t r64 = (size_t)64 * K;

#define STAGE(buf, slot, src, kt) do {                          \
        ushort* d_ = &lds[(buf) * 32768 + (slot) * 8192 + tid * 8]; \
        async16((src) + (kt), d_);                              \
        async16((src) + r64 + (kt), d_ + 4096);                 \
    } while (0)

    // swizzled fragment col for k-slice ks: (ks*16 + khi*8) ^ ((row&7)<<3)
    const int swz = (lane & 7) << 3;

    f32x16 acc[4][2];
#pragma unroll
    for (int mt = 0; mt < 4; ++mt)
#pragma unroll
        for (int nt = 0; nt < 2; ++nt)
#pragma unroll
            for (int r = 0; r < 16; ++r) acc[mt][nt][r] = 0.f;

    short8 af[2][4], bf[2][4];

    // LDA(base, pair): A fragments for mtiles {pair*2, pair*2+1}
    auto LDA = [&](int base, int pair) {
#pragma unroll
        for (int m = 0; m < 2; ++m)
#pragma unroll
            for (int ks = 0; ks < 4; ++ks)
                af[m][ks] = *(const short8*)&lds[base + wr * 8192 +
                                                 (pair * 2 + m) * 2048 + lrow * 64 +
                                                 ((ks * 16 + khi * 8) ^ swz)];
    };
    // LDB(base): both ntiles' fragments
    auto LDB = [&](int base) {
#pragma unroll
        for (int nt = 0; nt < 2; ++nt)
#pragma unroll
            for (int ks = 0; ks < 4; ++ks)
                bf[nt][ks] = *(const short8*)&lds[base + (2 + (wc >> 1)) * 8192 +
                                                  (wc & 1) * 4096 + nt * 2048 +
                                                  lrow * 64 +
                                                  ((ks * 16 + khi * 8) ^ swz)];
    };

#define MM8(MT, NT) do {                                                     \
        _Pragma("unroll")                                                    \
        for (int m_ = 0; m_ < 2; ++m_)                                       \
            _Pragma("unroll")                                                \
            for (int ks_ = 0; ks_ < 4; ++ks_)                                \
                acc[(MT) + m_][NT] = __builtin_amdgcn_mfma_f32_32x32x16_bf16( \
                    af[m_][ks_], bf[NT][ks_], acc[(MT) + m_][NT], 0, 0, 0);  \
    } while (0)

    // prologue: tile0 (buf0) fully + tile1 (buf1) 3 of 4 halves; order B0,B1,A0,A1
    STAGE(0, 2, gB, 0);  STAGE(0, 3, gB2, 0);  STAGE(0, 0, gA, 0);  STAGE(0, 1, gA2, 0);
    STAGE(1, 2, gB, 64); STAGE(1, 3, gB2, 64); STAGE(1, 0, gA, 64);
    VMC6();   // 14 issued, wait 8 oldest (= all of tile0)
    BAR();

    for (int it = 0; it < 31; ++it) {
        const int kt2 = it * 128 + 128, kt3 = kt2 + 64, ktn = kt2 - 64;
        // PH1: read A m01 + B all (tile t); stage t+1's A1
        LDA(0, 0); LDB(0);
        STAGE(1, 1, gA2, ktn);
        BAR(); LGKM0(); PRIO1(); MM8(0, 0); PRIO0(); BAR();
        // PH2: stage t+2 B0 (B slot fully read in PH1)
        STAGE(0, 2, gB, kt2);
        BAR(); LGKM0(); PRIO1(); MM8(0, 1); PRIO0(); BAR();
        // PH3: read A m23; stage t+2 B1
        LDA(0, 1);
        STAGE(0, 3, gB2, kt2);
        BAR(); LGKM0(); PRIO1(); MM8(2, 1); PRIO0(); BAR();
        // PH4: stage t+2 A0; counted vmcnt -> tile t+1 fully landed
        STAGE(0, 0, gA, kt2);
        VMC6();
        BAR(); LGKM0(); PRIO1(); MM8(2, 0); PRIO0(); BAR();
        // PH5: compute t+1 (buf1); stage t+2 A1
        LDA(32768, 0); LDB(32768);
        STAGE(0, 1, gA2, kt2);
        BAR(); LGKM0(); PRIO1(); MM8(0, 0); PRIO0(); BAR();
        // PH6: stage t+3 B0
        STAGE(1, 2, gB, kt3);
        BAR(); LGKM0(); PRIO1(); MM8(0, 1); PRIO0(); BAR();
        // PH7: stage t+3 B1
        LDA(32768, 1);
        STAGE(1, 3, gB2, kt3);
        BAR(); LGKM0(); PRIO1(); MM8(2, 1); PRIO0(); BAR();
        // PH8: stage t+3 A0; counted vmcnt -> tile t+2 fully landed
        STAGE(1, 0, gA, kt3);
        VMC6();
        BAR(); LGKM0(); PRIO1(); MM8(2, 0); PRIO0(); BAR();
    }

    // final iteration: tiles 62 (buf0, kt=3968) and 63 (buf1, kt=4032)
    {
        LDA(0, 0); LDB(0);
        STAGE(1, 1, gA2, 4032);      // last half of tile 63
        BAR(); LGKM0(); PRIO1(); MM8(0, 0); PRIO0(); BAR();
        BAR(); LGKM0(); PRIO1(); MM8(0, 1); PRIO0(); BAR();
        LDA(0, 1);
        BAR(); LGKM0(); PRIO1(); MM8(2, 1); PRIO0(); BAR();
        VMC0();                       // drain: tile 63 fully landed
        BAR(); LGKM0(); PRIO1(); MM8(2, 0); PRIO0(); BAR();
        LDA(32768, 0); LDB(32768);
        LGKM0(); PRIO1(); MM8(0, 0); PRIO0();
        PRIO1(); MM8(0, 1); PRIO0();
        LDA(32768, 1);
        LGKM0(); PRIO1(); MM8(2, 1); PRIO0();
        PRIO1(); MM8(2, 0); PRIO0();
    }

    // epilogue: 32x32 C/D layout (m74/m101): col=lane&31,
    // row = (reg&3) + 8*(reg>>2) + 4*(lane>>5)
#pragma unroll
    for (int nt = 0; nt < 2; ++nt) {
        const int col = bn * 256 + wc * 64 + nt * 32 + lrow;
        const float bv = bias[col];
#pragma unroll
        for (int mt = 0; mt < 4; ++mt) {
            const int rowb = bm * 256 + wr * 128 + mt * 32 + khi * 4;
#pragma unroll
            for (int reg = 0; reg < 16; ++reg) {
                const int row = rowb + (reg & 3) + 8 * (reg >> 2);
                C[(size_t)row * N + col] = acc[mt][nt][reg] + bv;
            }
        }
    }
#undef STAGE
#undef MM8
}

// ---------------------------------------------------------------------------
extern "C" void kernel_launch(void* const* d_in, const int* in_sizes, int n_in,
                              void* d_out, int out_size, void* d_ws, size_t ws_size,
                              hipStream_t stream) {
    const float* x    = (const float*)d_in[0];   // (4,2048,4096) f32
    const float* c    = (const float*)d_in[1];   // (16,16,256) f32
    const float* bias = (const float*)d_in[2];   // (4096,) f32
    float* out = (float*)d_out;                  // (4,2048,4096) f32

    ushort* Wb = (ushort*)d_ws;                  // 32 MiB
    ushort* Xb = Wb + (size_t)4096 * 4096;       // 64 MiB

    hipLaunchKernelGGL(expand_w, dim3(256), dim3(256), 0, stream, c, Wb);
    hipLaunchKernelGGL(conv_x, dim3(2048), dim3(256), 0, stream,
                       (const float4*)x, (u16x8*)Xb, 33554432 / 8);
    hipLaunchKernelGGL(gemm256, dim3(512), dim3(512), 0, stream,
                       Xb, Wb, bias, out);
}